// Round 3
// baseline (442.937 us; speedup 1.0000x reference)
//
#include <hip/hip_runtime.h>

#define NN 20000
#define EE 320000

// consts layout (float offsets)
#define WZ_O 0
#define BZ_O 512
#define WH_O 576
#define BH_O 1088
#define OW_O 1152
#define OB_O 1920
#define PR_O 1932
#define NCONST 1944

__device__ __forceinline__ float b2f(unsigned short h) {
  union { unsigned int u; float f; } v; v.u = ((unsigned int)h) << 16; return v.f;
}
__device__ __forceinline__ unsigned short f2b(float f) {
  union { unsigned int u; float f; } v; v.f = f;
  unsigned int u = v.u;
  unsigned int r = (u + 0x7fffu + ((u >> 16) & 1u)) >> 16;  // RNE
  return (unsigned short)r;
}
__device__ __forceinline__ float ldw(const void* p, int i, int isbf) {
  return isbf ? b2f(((const unsigned short*)p)[i]) : ((const float*)p)[i];
}

// 0) dtype detection from raw bit patterns
__global__ void k_detect(const unsigned int* __restrict__ ei_w,
                         const unsigned int* __restrict__ ea_w,
                         int* __restrict__ flags) {
  int t = threadIdx.x;  // 64 threads
  // edge_attr in (0,1): packed-bf16 words have bits 15/31 == 0 (signs); f32 words random bit15
  unsigned long long b1 = __ballot((ea_w[t] >> 15) & 1u);
  // edge_index < 20000: int64 arrays have all odd 32-bit words == 0
  unsigned long long b2 = __ballot(ei_w[2 * t + 1] != 0u);
  if (t == 0) {
    flags[0] = (b1 == 0ull) ? 1 : 0;  // 1 = floats are bf16
    flags[1] = (b2 == 0ull) ? 1 : 0;  // 1 = indices are int64
  }
}

// 1) zero deg/count
__global__ void k_zero(float* __restrict__ deg, int* __restrict__ count) {
  int i = blockIdx.x * blockDim.x + threadIdx.x;
  if (i < NN) { deg[i] = 0.0f; count[i] = 0; }
}

// 2) histogram: weighted degree (for dinv) and in-edge count (for CSR)
__global__ void k_deg_count(const void* __restrict__ ei, const void* __restrict__ ea,
                            const int* __restrict__ flags,
                            float* __restrict__ deg, int* __restrict__ count) {
  int isbf = flags[0], is64 = flags[1];
  int e = blockIdx.x * blockDim.x + threadIdx.x;
  if (e < EE) {
    int c = is64 ? (int)((const unsigned int*)ei)[2 * (EE + e)]
                 : ((const int*)ei)[EE + e];
    float w = isbf ? b2f(((const unsigned short*)ea)[e]) : ((const float*)ea)[e];
    atomicAdd(&deg[c], w);
    atomicAdd(&count[c], 1);
  }
}

// 3) single block: scan -> row_start/cursor ; dinv ; fused weight prep
__global__ void k_scan_prep(const int* __restrict__ count, int* __restrict__ row_start,
                            int* __restrict__ cursor, const float* __restrict__ deg,
                            float* __restrict__ dinv, float* __restrict__ consts,
                            const int* __restrict__ flags,
                            const void* czw, const void* czb,
                            const void* chw, const void* chb,
                            const void* lzw, const void* lzb,
                            const void* lhw, const void* lhb,
                            const void* att, const void* ow, const void* ob) {
  __shared__ int sm[256];
  int isbf = flags[0];
  int tid = threadIdx.x;
  const int CH = 79;                   // ceil(20000/256)
  int lo = tid * CH;
  int hi = (lo + CH < NN) ? (lo + CH) : NN;
  if (lo > NN) lo = NN;
  int s = 0;
  for (int i = lo; i < hi; ++i) s += count[i];
  sm[tid] = s; __syncthreads();
  for (int off = 1; off < 256; off <<= 1) {
    int v = (tid >= off) ? sm[tid - off] : 0;
    __syncthreads();
    sm[tid] += v;
    __syncthreads();
  }
  int base = sm[tid] - s;              // exclusive prefix
  for (int i = lo; i < hi; ++i) { row_start[i] = base; cursor[i] = base; base += count[i]; }
  if (tid == 0) row_start[NN] = sm[255];
  for (int i = tid; i < NN; i += 256) dinv[i] = rsqrtf(deg[i] + 1.0f);
  // fused gate weights: Wz = conv_z_w @ lin_z_w[:64], Wh = conv_h_w @ lin_h_w[:64]
  for (int i = tid; i < 512; i += 256) {
    int f = i >> 6, k = i & 63;
    float sz = 0.f, sh = 0.f;
    for (int h = 0; h < 64; ++h) {
      sz += ldw(czw, f * 64 + h, isbf) * ldw(lzw, h * 64 + k, isbf);
      sh += ldw(chw, f * 64 + h, isbf) * ldw(lhw, h * 64 + k, isbf);
    }
    consts[WZ_O + i] = sz; consts[WH_O + i] = sh;
  }
  for (int i = tid; i < 64; i += 256) {
    float sz = ldw(lzb, i, isbf), sh = ldw(lhb, i, isbf);
    for (int h = 0; h < 64; ++h) {
      sz += ldw(czb, h, isbf) * ldw(lzw, h * 64 + i, isbf);
      sh += ldw(chb, h, isbf) * ldw(lhw, h * 64 + i, isbf);
    }
    consts[BZ_O + i] = sz; consts[BH_O + i] = sh;
  }
  for (int i = tid; i < 768; i += 256) consts[OW_O + i] = ldw(ow, i, isbf);
  if (tid < 12) consts[OB_O + tid] = ldw(ob, tid, isbf);
  if (tid == 0) {
    float a[12]; float m = -1e30f;
    for (int p = 0; p < 12; ++p) { a[p] = ldw(att, p, isbf); m = fmaxf(m, a[p]); }
    float ssum = 0.f;
    for (int p = 0; p < 12; ++p) { a[p] = __expf(a[p] - m); ssum += a[p]; }
    for (int p = 0; p < 12; ++p) consts[PR_O + p] = a[p] / ssum;
  }
}

// 4) CSR scatter: store src and w*dinv[src]
__global__ void k_scatter(const void* __restrict__ ei, const void* __restrict__ ea,
                          const int* __restrict__ flags, const float* __restrict__ dinv,
                          int* __restrict__ cursor, int* __restrict__ csr_src,
                          float* __restrict__ csr_val) {
  int isbf = flags[0], is64 = flags[1];
  int e = blockIdx.x * blockDim.x + threadIdx.x;
  if (e < EE) {
    int r = is64 ? (int)((const unsigned int*)ei)[2 * e] : ((const int*)ei)[e];
    int c = is64 ? (int)((const unsigned int*)ei)[2 * (EE + e)] : ((const int*)ei)[EE + e];
    float w = isbf ? b2f(((const unsigned short*)ea)[e]) : ((const float*)ea)[e];
    int pos = atomicAdd(&cursor[c], 1);
    csr_src[pos] = r;
    csr_val[pos] = w * dinv[r];
  }
}

// 5) fused per-node: gather-aggregate (direct from x) -> gates -> weighted accum -> relu -> proj
__global__ void __launch_bounds__(192) k_node(
    const void* __restrict__ x,
    const int* __restrict__ row_start, const int* __restrict__ csr_src,
    const float* __restrict__ csr_val, const float* __restrict__ dinv,
    const float* __restrict__ consts, const int* __restrict__ flags,
    void* __restrict__ out) {
  __shared__ float sc[NCONST];
  __shared__ float acc[384];
  __shared__ float hpart[768];   // [g][b][k]
  __shared__ float hfin[256];    // [b][k]
  int tid = threadIdx.x;
  int n = blockIdx.x;
  int isbf = flags[0];
  for (int i = tid; i < NCONST; i += 192) sc[i] = consts[i];

  // thread owns payload elems (e2, e2+1) of the 384-elem [b][f][p] block
  const int e2 = 2 * tid;
  const int bsel = e2 / 96;            // batch
  const int r = e2 % 96;               // even offset within [f][p] (96 elems)
  const long cbase = (long)bsel * NN * 96 + r;  // + s*96 -> element index in x[b][s][f][p]

  int beg = row_start[n], end = row_start[n + 1];
  float a0 = 0.f, a1 = 0.f;
  if (isbf) {
    const unsigned short* xb = (const unsigned short*)x;
    for (int i = beg; i < end; ++i) {
      int s = csr_src[i];              // uniform across block
      float v = csr_val[i];
      unsigned int xx = *(const unsigned int*)(xb + cbase + (long)s * 96);
      a0 += v * b2f((unsigned short)(xx & 0xffffu));
      a1 += v * b2f((unsigned short)(xx >> 16));
    }
    float dn = dinv[n];
    unsigned int xs = *(const unsigned int*)(xb + cbase + (long)n * 96);
    a0 = dn * a0 + dn * dn * b2f((unsigned short)(xs & 0xffffu));   // + self loop (w=1)
    a1 = dn * a1 + dn * dn * b2f((unsigned short)(xs >> 16));
  } else {
    const float* xf = (const float*)x;
    for (int i = beg; i < end; ++i) {
      int s = csr_src[i];
      float v = csr_val[i];
      float2 xx = *(const float2*)(xf + cbase + (long)s * 96);
      a0 += v * xx.x;
      a1 += v * xx.y;
    }
    float dn = dinv[n];
    float2 xs = *(const float2*)(xf + cbase + (long)n * 96);
    a0 = dn * a0 + dn * dn * xs.x;
    a1 = dn * a1 + dn * dn * xs.y;
  }
  acc[e2] = a0; acc[e2 + 1] = a1;
  __syncthreads();

  // --- gates: group g handles p in {g, g+3, g+6, g+9}, all b; k = lane ---
  int k = tid & 63, g = tid >> 6;
  float hb0 = 0.f, hb1 = 0.f, hb2 = 0.f, hb3 = 0.f;
#pragma unroll
  for (int pi = 0; pi < 4; ++pi) {
    int p = g + 3 * pi;
    float pr = sc[PR_O + p];
#pragma unroll
    for (int b = 0; b < 4; ++b) {
      float za = sc[BZ_O + k], ta = sc[BH_O + k];
#pragma unroll
      for (int f = 0; f < 8; ++f) {
        float a = acc[b * 96 + f * 12 + p];
        za += a * sc[WZ_O + f * 64 + k];
        ta += a * sc[WH_O + f * 64 + k];
      }
      float z  = 1.0f / (1.0f + __expf(-za));
      float th = 1.0f - 2.0f / (1.0f + __expf(2.0f * ta));
      float c = pr * (1.0f - z) * th;    // (1-Z)*Ht ; Z*H0 term is zero
      if (b == 0) hb0 += c; else if (b == 1) hb1 += c; else if (b == 2) hb2 += c; else hb3 += c;
    }
  }
  hpart[g * 256 +   0 + k] = hb0;
  hpart[g * 256 +  64 + k] = hb1;
  hpart[g * 256 + 128 + k] = hb2;
  hpart[g * 256 + 192 + k] = hb3;
  __syncthreads();

  for (int i = tid; i < 256; i += 192) {
    float h = hpart[i] + hpart[256 + i] + hpart[512 + i];
    hfin[i] = fmaxf(h, 0.f);
  }
  __syncthreads();

  if (tid < 48) {
    int b = tid / 12, p = tid % 12;
    float o = sc[OB_O + p];
#pragma unroll 8
    for (int k2 = 0; k2 < 64; ++k2) o += hfin[b * 64 + k2] * sc[OW_O + k2 * 12 + p];
    int oi = (b * NN + n) * 12 + p;
    if (isbf) ((unsigned short*)out)[oi] = f2b(o);
    else      ((float*)out)[oi] = o;
  }
}

extern "C" void kernel_launch(void* const* d_in, const int* in_sizes, int n_in,
                              void* d_out, int out_size, void* d_ws, size_t ws_size,
                              hipStream_t stream) {
  const void* x   = d_in[0];
  const void* ei  = d_in[1];
  const void* ea  = d_in[2];
  const void* czw = d_in[3];
  const void* czb = d_in[4];
  // d_in[5], d_in[6]: conv_r_* — dead (H0 = 0)
  const void* chw = d_in[7];
  const void* chb = d_in[8];
  const void* lzw = d_in[9];
  const void* lzb = d_in[10];
  // d_in[11], d_in[12]: lin_r_* — dead
  const void* lhw = d_in[13];
  const void* lhb = d_in[14];
  const void* att = d_in[15];
  const void* ow  = d_in[16];
  const void* ob  = d_in[17];

  // compact workspace: < 3 MB total (never assume ws_size is large)
  char* ws = (char*)d_ws;
  int*   flags   = (int*)  (ws + 0);          // 2 ints
  float* consts  = (float*)(ws + 256);        // 1944 f32 -> ends 8032
  float* deg     = (float*)(ws + 8192);       // 20000 f32 -> 88192
  float* dinv    = (float*)(ws + 88192);      // 20000 f32 -> 168192
  int*   count   = (int*)  (ws + 168192);     // 20000 i32 -> 248192
  int*   row_st  = (int*)  (ws + 248192);     // 20001 i32 -> 328196
  int*   cursor  = (int*)  (ws + 328448);     // 20000 i32 -> 408448
  int*   csr_src = (int*)  (ws + 408448);     // 320000 i32 -> 1688448
  float* csr_val = (float*)(ws + 1688448);    // 320000 f32 -> 2968448 (~2.97 MB)

  k_detect<<<dim3(1), dim3(64), 0, stream>>>((const unsigned int*)ei,
                                             (const unsigned int*)ea, flags);
  k_zero<<<dim3(79), dim3(256), 0, stream>>>(deg, count);
  k_deg_count<<<dim3(1250), dim3(256), 0, stream>>>(ei, ea, flags, deg, count);
  k_scan_prep<<<dim3(1), dim3(256), 0, stream>>>(count, row_st, cursor, deg, dinv, consts,
                                                 flags, czw, czb, chw, chb, lzw, lzb,
                                                 lhw, lhb, att, ow, ob);
  k_scatter<<<dim3(1250), dim3(256), 0, stream>>>(ei, ea, flags, dinv, cursor,
                                                  csr_src, csr_val);
  k_node<<<dim3(20000), dim3(192), 0, stream>>>(x, row_st, csr_src, csr_val, dinv,
                                                consts, flags, d_out);
}

// Round 5
// 348.373 us; speedup vs baseline: 1.2714x; 1.2714x over previous
//
#include <hip/hip_runtime.h>

#define NN 20000
#define EE 320000
#define NPB 8

// consts layout (float offsets)
#define WZ_O 0
#define BZ_O 512
#define WH_O 576
#define BH_O 1088
#define OW_O 1152
#define OB_O 1920
#define PR_O 1932
#define NCONST 1944

__device__ __forceinline__ float b2f(unsigned short h) {
  union { unsigned int u; float f; } v; v.u = ((unsigned int)h) << 16; return v.f;
}
__device__ __forceinline__ unsigned short f2b(float f) {
  union { unsigned int u; float f; } v; v.f = f;
  unsigned int u = v.u;
  unsigned int r = (u + 0x7fffu + ((u >> 16) & 1u)) >> 16;  // RNE
  return (unsigned short)r;
}
__device__ __forceinline__ float ldw(const void* p, int i, int isbf) {
  return isbf ? b2f(((const unsigned short*)p)[i]) : ((const float*)p)[i];
}
// unpack a 32-bit word holding two bf16 -> two f32
__device__ __forceinline__ void upk(unsigned int w, float& x0, float& x1) {
  union { unsigned int u; float f; } lo, hi;
  lo.u = w << 16; hi.u = w & 0xffff0000u;
  x0 = lo.f; x1 = hi.f;
}

// 1) init: zero packed deg/count histogram; block 0 also: dtype-detect + fused-weight prep
__global__ void k_init(const unsigned int* __restrict__ ei_w,
                       const unsigned int* __restrict__ ea_w,
                       int* __restrict__ flags,
                       unsigned long long* __restrict__ degcnt,
                       float* __restrict__ consts,
                       const void* czw, const void* czb,
                       const void* chw, const void* chb,
                       const void* lzw, const void* lzb,
                       const void* lhw, const void* lhb,
                       const void* att, const void* ow, const void* ob) {
  int tid = threadIdx.x;
  int i = blockIdx.x * 256 + tid;
  if (i < NN) degcnt[i] = 0ull;
  if (blockIdx.x != 0) return;

  __shared__ int sfl[2];
  if (tid < 64) {
    // edge_attr in (0,1): packed-bf16 words have sign bits 15/31 == 0; f32 words random bit15
    unsigned long long b1 = __ballot((ea_w[tid] >> 15) & 1u);
    // edge_index < 20000: int64 arrays have all odd 32-bit words == 0
    unsigned long long b2 = __ballot(ei_w[2 * tid + 1] != 0u);
    if (tid == 0) {
      int f0 = (b1 == 0ull) ? 1 : 0;   // 1 = floats are bf16
      int f1 = (b2 == 0ull) ? 1 : 0;   // 1 = indices are int64
      flags[0] = f0; flags[1] = f1; sfl[0] = f0; sfl[1] = f1;
    }
  }
  __syncthreads();
  int isbf = sfl[0];

  // fused gate weights: Wz = conv_z_w @ lin_z_w[:64], Wh = conv_h_w @ lin_h_w[:64]
  for (int idx = tid; idx < 512; idx += 256) {
    int f = idx >> 6, k = idx & 63;
    float sz = 0.f, sh = 0.f;
    for (int h = 0; h < 64; ++h) {
      sz += ldw(czw, f * 64 + h, isbf) * ldw(lzw, h * 64 + k, isbf);
      sh += ldw(chw, f * 64 + h, isbf) * ldw(lhw, h * 64 + k, isbf);
    }
    consts[WZ_O + idx] = sz; consts[WH_O + idx] = sh;
  }
  for (int idx = tid; idx < 64; idx += 256) {
    float sz = ldw(lzb, idx, isbf), sh = ldw(lhb, idx, isbf);
    for (int h = 0; h < 64; ++h) {
      sz += ldw(czb, h, isbf) * ldw(lzw, h * 64 + idx, isbf);
      sh += ldw(chb, h, isbf) * ldw(lhw, h * 64 + idx, isbf);
    }
    consts[BZ_O + idx] = sz; consts[BH_O + idx] = sh;
  }
  for (int idx = tid; idx < 768; idx += 256) consts[OW_O + idx] = ldw(ow, idx, isbf);
  if (tid < 12) consts[OB_O + tid] = ldw(ob, tid, isbf);
  if (tid == 0) {
    float a[12]; float m = -1e30f;
    for (int p = 0; p < 12; ++p) { a[p] = ldw(att, p, isbf); m = fmaxf(m, a[p]); }
    float ssum = 0.f;
    for (int p = 0; p < 12; ++p) { a[p] = __expf(a[p] - m); ssum += a[p]; }
    for (int p = 0; p < 12; ++p) consts[PR_O + p] = a[p] / ssum;
  }
}

// 2) histogram: one packed 64-bit atomic per edge (count in hi32, fixed-point deg in lo32)
__global__ void k_deg_count(const void* __restrict__ ei, const void* __restrict__ ea,
                            const int* __restrict__ flags,
                            unsigned long long* __restrict__ degcnt) {
  int isbf = flags[0], is64 = flags[1];
  int e = blockIdx.x * blockDim.x + threadIdx.x;
  if (e < EE) {
    int c = is64 ? (int)((const unsigned int*)ei)[2 * (EE + e)]
                 : ((const int*)ei)[EE + e];
    float w = isbf ? b2f(((const unsigned short*)ea)[e]) : ((const float*)ea)[e];
    unsigned long long pk = (1ull << 32) |
        (unsigned long long)(unsigned int)__float2int_rn(w * 1048576.0f);
    atomicAdd(&degcnt[c], pk);
  }
}

// 3) single block: scan counts -> row_start/cursor ; dinv from fixed-point deg
__global__ void k_scan(const unsigned long long* __restrict__ degcnt,
                       int* __restrict__ row_start, int* __restrict__ cursor,
                       float* __restrict__ dinv) {
  __shared__ int sm[256];
  int tid = threadIdx.x;
  const int CH = 79;                   // ceil(20000/256)
  int lo = tid * CH; if (lo > NN) lo = NN;
  int hi = lo + CH; if (hi > NN) hi = NN;
  int s = 0;
  for (int i = lo; i < hi; ++i) s += (int)(degcnt[i] >> 32);
  sm[tid] = s; __syncthreads();
  for (int off = 1; off < 256; off <<= 1) {
    int v = (tid >= off) ? sm[tid - off] : 0;
    __syncthreads();
    sm[tid] += v;
    __syncthreads();
  }
  int base = sm[tid] - s;              // exclusive prefix
  for (int i = lo; i < hi; ++i) {
    int cnt = (int)(degcnt[i] >> 32);
    row_start[i] = base; cursor[i] = base; base += cnt;
  }
  if (tid == 0) row_start[NN] = sm[255];
  for (int i = tid; i < NN; i += 256) {
    float dg = (float)(unsigned int)degcnt[i] * (1.0f / 1048576.0f);
    dinv[i] = rsqrtf(dg + 1.0f);       // +1 for self loop
  }
}

// 4) CSR scatter: store src and w*dinv[src]
__global__ void k_scatter(const void* __restrict__ ei, const void* __restrict__ ea,
                          const int* __restrict__ flags, const float* __restrict__ dinv,
                          int* __restrict__ cursor, int* __restrict__ csr_src,
                          float* __restrict__ csr_val) {
  int isbf = flags[0], is64 = flags[1];
  int e = blockIdx.x * blockDim.x + threadIdx.x;
  if (e < EE) {
    int r = is64 ? (int)((const unsigned int*)ei)[2 * e] : ((const int*)ei)[e];
    int c = is64 ? (int)((const unsigned int*)ei)[2 * (EE + e)] : ((const int*)ei)[EE + e];
    float w = isbf ? b2f(((const unsigned short*)ea)[e]) : ((const float*)ea)[e];
    int pos = atomicAdd(&cursor[c], 1);
    csr_src[pos] = r;
    csr_val[pos] = w * dinv[r];
  }
}

// 5) fused per-node pipeline, NPB nodes per block, 192 threads.
//    gather: 4 edge-subgroups x 48 threads, 16B/lane; CSR staged in LDS.
//    x layout is [b][n][f][p]: per-node payload = 4 segments of 96 elems, stride NN*96.
__global__ void __launch_bounds__(192) k_node(
    const void* __restrict__ x,
    const int* __restrict__ row_start, const int* __restrict__ csr_src,
    const float* __restrict__ csr_val, const float* __restrict__ dinv,
    const float* __restrict__ consts, const int* __restrict__ flags,
    void* __restrict__ out) {
  __shared__ __align__(16) float sc[NCONST];
  __shared__ __align__(16) float pacc[4 * 384];
  __shared__ __align__(16) float acc[384];     // [b][p][f]
  __shared__ __align__(16) float hpart[768];   // [g3][b][k]
  __shared__ __align__(16) float hfin[256];    // [b][k]
  __shared__ int   sedge[192];
  __shared__ float vedge[192];

  const int tid = threadIdx.x;
  const int isbf = flags[0];
  for (int i = tid; i < NCONST; i += 192) sc[i] = consts[i];

  const int g  = tid / 48;      // edge subgroup 0..3
  const int c  = tid % 48;      // payload chunk: flat elems 8c..8c+7 of [b][f][p]
  const int k  = tid & 63;      // gate lane (hidden dim)
  const int g3 = tid >> 6;      // gate p-group 0..2

  // chunk -> (batch, within-batch offset); chunks never cross batch (96 % 8 == 0)
  const int bc = c / 12;                       // batch of this chunk
  const int oc = 8 * (c % 12);                 // elem offset within [f][p] block
  const long xoff = (long)bc * (NN * 96) + oc; // + s*96 -> elem index in x[b][s][f][p]

  __syncthreads();
  float wz[8], wh[8];
#pragma unroll
  for (int f = 0; f < 8; ++f) {
    wz[f] = sc[WZ_O + f * 64 + k];
    wh[f] = sc[WH_O + f * 64 + k];
  }
  const float bz = sc[BZ_O + k], bh = sc[BH_O + k];

  const int n0 = blockIdx.x * NPB;
  for (int ni = 0; ni < NPB; ++ni) {
    const int n = n0 + ni;
    const int beg = row_start[n], end = row_start[n + 1];
    const float dn = dinv[n];
    float a[8];
#pragma unroll
    for (int t = 0; t < 8; ++t) a[t] = 0.f;

    for (int i0 = beg; i0 < end; i0 += 192) {
      int m = end - i0; if (m > 192) m = 192;
      if (tid < m) { sedge[tid] = csr_src[i0 + tid]; vedge[tid] = csr_val[i0 + tid]; }
      __syncthreads();
      if (isbf) {
        const unsigned short* xb = (const unsigned short*)x;
        for (int j = g; j < m; j += 4) {
          int s = sedge[j]; float v = vedge[j];
          uint4 u = *(const uint4*)(xb + xoff + (long)s * 96);
          float x0, x1;
          upk(u.x, x0, x1); a[0] += v * x0; a[1] += v * x1;
          upk(u.y, x0, x1); a[2] += v * x0; a[3] += v * x1;
          upk(u.z, x0, x1); a[4] += v * x0; a[5] += v * x1;
          upk(u.w, x0, x1); a[6] += v * x0; a[7] += v * x1;
        }
      } else {
        const float* xf = (const float*)x;
        for (int j = g; j < m; j += 4) {
          int s = sedge[j]; float v = vedge[j];
          const float4* px = (const float4*)(xf + xoff + (long)s * 96);
          float4 u0 = px[0], u1 = px[1];
          a[0] += v * u0.x; a[1] += v * u0.y; a[2] += v * u0.z; a[3] += v * u0.w;
          a[4] += v * u1.x; a[5] += v * u1.y; a[6] += v * u1.z; a[7] += v * u1.w;
        }
      }
      __syncthreads();
    }
    // self loop (weight 1): subgroup 0 only; outer dn -> dn^2 * x[n]
    if (g == 0) {
      if (isbf) {
        const unsigned short* xb = (const unsigned short*)x;
        uint4 u = *(const uint4*)(xb + xoff + (long)n * 96);
        float x0, x1;
        upk(u.x, x0, x1); a[0] += dn * x0; a[1] += dn * x1;
        upk(u.y, x0, x1); a[2] += dn * x0; a[3] += dn * x1;
        upk(u.z, x0, x1); a[4] += dn * x0; a[5] += dn * x1;
        upk(u.w, x0, x1); a[6] += dn * x0; a[7] += dn * x1;
      } else {
        const float* xf = (const float*)x;
        const float4* px = (const float4*)(xf + xoff + (long)n * 96);
        float4 u0 = px[0], u1 = px[1];
        a[0] += dn * u0.x; a[1] += dn * u0.y; a[2] += dn * u0.z; a[3] += dn * u0.w;
        a[4] += dn * u1.x; a[5] += dn * u1.y; a[6] += dn * u1.z; a[7] += dn * u1.w;
      }
    }
    {
      float4* pg = (float4*)&pacc[g * 384 + 8 * c];
      pg[0] = make_float4(a[0], a[1], a[2], a[3]);
      pg[1] = make_float4(a[4], a[5], a[6], a[7]);
    }
    __syncthreads();
    // combine 4 partials + scale by dinv[n]; transpose [b][f][p] -> [b][p][f]
    for (int i = tid; i < 384; i += 192) {
      int b = i / 96, r = i % 96, p = r >> 3, f = r & 7;
      int src = b * 96 + f * 12 + p;
      acc[i] = dn * (pacc[src] + pacc[384 + src] + pacc[768 + src] + pacc[1152 + src]);
    }
    __syncthreads();

    // gates: g3 handles p in {g3, g3+3, g3+6, g3+9}; k = hidden index
    float hb0 = 0.f, hb1 = 0.f, hb2 = 0.f, hb3 = 0.f;
#pragma unroll
    for (int pi = 0; pi < 4; ++pi) {
      int p = g3 + 3 * pi;
      float pr = sc[PR_O + p];
#pragma unroll
      for (int b = 0; b < 4; ++b) {
        const float4* A = (const float4*)&acc[b * 96 + p * 8];
        float4 A0 = A[0], A1 = A[1];
        float za = bz + A0.x * wz[0] + A0.y * wz[1] + A0.z * wz[2] + A0.w * wz[3]
                      + A1.x * wz[4] + A1.y * wz[5] + A1.z * wz[6] + A1.w * wz[7];
        float ta = bh + A0.x * wh[0] + A0.y * wh[1] + A0.z * wh[2] + A0.w * wh[3]
                      + A1.x * wh[4] + A1.y * wh[5] + A1.z * wh[6] + A1.w * wh[7];
        // (1 - sigmoid(za)) * tanh(ta) = (eh-1) / ((1+ea)(1+eh)), ea=e^za, eh=e^{2ta}
        float ea = __expf(za);
        float eh = __expf(2.0f * fminf(ta, 40.0f));
        float cc = pr * (eh - 1.0f) * __builtin_amdgcn_rcpf((1.0f + ea) * (1.0f + eh));
        if (b == 0) hb0 += cc; else if (b == 1) hb1 += cc;
        else if (b == 2) hb2 += cc; else hb3 += cc;
      }
    }
    hpart[g3 * 256 +   0 + k] = hb0;
    hpart[g3 * 256 +  64 + k] = hb1;
    hpart[g3 * 256 + 128 + k] = hb2;
    hpart[g3 * 256 + 192 + k] = hb3;
    __syncthreads();
    for (int i = tid; i < 256; i += 192)
      hfin[i] = fmaxf(hpart[i] + hpart[256 + i] + hpart[512 + i], 0.f);
    __syncthreads();

    if (tid < 48) {
      int b = tid / 12, p = tid % 12;
      float o = sc[OB_O + p];
#pragma unroll 8
      for (int k2 = 0; k2 < 64; ++k2) o += hfin[b * 64 + k2] * sc[OW_O + k2 * 12 + p];
      int oi = (b * NN + n) * 12 + p;
      if (isbf) ((unsigned short*)out)[oi] = f2b(o);
      else      ((float*)out)[oi] = o;
    }
  }
}

extern "C" void kernel_launch(void* const* d_in, const int* in_sizes, int n_in,
                              void* d_out, int out_size, void* d_ws, size_t ws_size,
                              hipStream_t stream) {
  const void* x   = d_in[0];
  const void* ei  = d_in[1];
  const void* ea  = d_in[2];
  const void* czw = d_in[3];
  const void* czb = d_in[4];
  // d_in[5], d_in[6]: conv_r_* — dead (H0 = 0)
  const void* chw = d_in[7];
  const void* chb = d_in[8];
  const void* lzw = d_in[9];
  const void* lzb = d_in[10];
  // d_in[11], d_in[12]: lin_r_* — dead
  const void* lhw = d_in[13];
  const void* lhb = d_in[14];
  const void* att = d_in[15];
  const void* ow  = d_in[16];
  const void* ob  = d_in[17];

  // compact workspace: < 3 MB total
  char* ws = (char*)d_ws;
  int*   flags   = (int*)  (ws + 0);
  float* consts  = (float*)(ws + 256);        // 1944 f32
  unsigned long long* degcnt = (unsigned long long*)(ws + 8192);  // 20000 u64
  float* dinv    = (float*)(ws + 168192);     // 20000 f32
  int*   row_st  = (int*)  (ws + 248192);     // 20001 i32
  int*   cursor  = (int*)  (ws + 328448);     // 20000 i32
  int*   csr_src = (int*)  (ws + 408448);     // 320000 i32
  float* csr_val = (float*)(ws + 1688448);    // 320000 f32 -> ends 2968448

  k_init<<<dim3(79), dim3(256), 0, stream>>>((const unsigned int*)ei,
                                             (const unsigned int*)ea, flags, degcnt,
                                             consts, czw, czb, chw, chb, lzw, lzb,
                                             lhw, lhb, att, ow, ob);
  k_deg_count<<<dim3(1250), dim3(256), 0, stream>>>(ei, ea, flags, degcnt);
  k_scan<<<dim3(1), dim3(256), 0, stream>>>(degcnt, row_st, cursor, dinv);
  k_scatter<<<dim3(1250), dim3(256), 0, stream>>>(ei, ea, flags, dinv, cursor,
                                                  csr_src, csr_val);
  k_node<<<dim3(NN / NPB), dim3(192), 0, stream>>>(x, row_st, csr_src, csr_val, dinv,
                                                   consts, flags, d_out);
}

// Round 6
// 260.233 us; speedup vs baseline: 1.7021x; 1.3387x over previous
//
#include <hip/hip_runtime.h>

#define NN 20000
#define EE 320000
#define NPB 8
#define CAP 64           // slab slots per node (in-degree ~ Poisson(16))
#define LCAP 80          // LDS per-node edge capacity (CAP + overflow slack)
#define OVCAP 8192

// consts layout (float offsets)
#define WZ_O 0
#define BZ_O 512
#define WH_O 576
#define BH_O 1088
#define OW_O 1152
#define OB_O 1920
#define PR_O 1932
#define NCONST 1944

__device__ __forceinline__ float b2f(unsigned short h) {
  union { unsigned int u; float f; } v; v.u = ((unsigned int)h) << 16; return v.f;
}
__device__ __forceinline__ unsigned short f2b(float f) {
  union { unsigned int u; float f; } v; v.f = f;
  unsigned int u = v.u;
  unsigned int r = (u + 0x7fffu + ((u >> 16) & 1u)) >> 16;  // RNE
  return (unsigned short)r;
}
__device__ __forceinline__ float ldw(const void* p, int i, int isbf) {
  return isbf ? b2f(((const unsigned short*)p)[i]) : ((const float*)p)[i];
}
__device__ __forceinline__ void upk(unsigned int w, float& x0, float& x1) {
  union { unsigned int u; float f; } lo, hi;
  lo.u = w << 16; hi.u = w & 0xffff0000u;
  x0 = lo.f; x1 = hi.f;
}
__device__ __forceinline__ float degf(unsigned long long dc) {
  return (float)(unsigned int)dc * (1.0f / 1048576.0f);
}

// 1) init: zero degcnt + ovf_cnt; block 0: dtype detect + fused-weight prep
__global__ void k_init(const unsigned int* __restrict__ ei_w,
                       const unsigned int* __restrict__ ea_w,
                       int* __restrict__ flags,
                       unsigned long long* __restrict__ degcnt,
                       int* __restrict__ ovf_cnt,
                       float* __restrict__ consts,
                       const void* czw, const void* czb,
                       const void* chw, const void* chb,
                       const void* lzw, const void* lzb,
                       const void* lhw, const void* lhb,
                       const void* att, const void* ow, const void* ob) {
  int tid = threadIdx.x;
  int i = blockIdx.x * 256 + tid;
  if (i < NN) degcnt[i] = 0ull;
  if (blockIdx.x == 1 && tid == 0) *ovf_cnt = 0;
  if (blockIdx.x != 0) return;

  __shared__ int sfl[2];
  if (tid < 64) {
    // edge_attr in (0,1): packed-bf16 words have sign bits 15/31 == 0; f32 words random bit15
    unsigned long long b1 = __ballot((ea_w[tid] >> 15) & 1u);
    // edge_index < 20000: int64 arrays have all odd 32-bit words == 0
    unsigned long long b2 = __ballot(ei_w[2 * tid + 1] != 0u);
    if (tid == 0) {
      int f0 = (b1 == 0ull) ? 1 : 0;   // 1 = floats are bf16
      int f1 = (b2 == 0ull) ? 1 : 0;   // 1 = indices are int64
      flags[0] = f0; flags[1] = f1; sfl[0] = f0; sfl[1] = f1;
    }
  }
  __syncthreads();
  int isbf = sfl[0];

  // fused gate weights: Wz = conv_z_w @ lin_z_w[:64], Wh = conv_h_w @ lin_h_w[:64]
  for (int idx = tid; idx < 512; idx += 256) {
    int f = idx >> 6, k = idx & 63;
    float sz = 0.f, sh = 0.f;
    for (int h = 0; h < 64; ++h) {
      sz += ldw(czw, f * 64 + h, isbf) * ldw(lzw, h * 64 + k, isbf);
      sh += ldw(chw, f * 64 + h, isbf) * ldw(lhw, h * 64 + k, isbf);
    }
    consts[WZ_O + idx] = sz; consts[WH_O + idx] = sh;
  }
  for (int idx = tid; idx < 64; idx += 256) {
    float sz = ldw(lzb, idx, isbf), sh = ldw(lhb, idx, isbf);
    for (int h = 0; h < 64; ++h) {
      sz += ldw(czb, h, isbf) * ldw(lzw, h * 64 + idx, isbf);
      sh += ldw(chb, h, isbf) * ldw(lhw, h * 64 + idx, isbf);
    }
    consts[BZ_O + idx] = sz; consts[BH_O + idx] = sh;
  }
  for (int idx = tid; idx < 768; idx += 256) consts[OW_O + idx] = ldw(ow, idx, isbf);
  if (tid < 12) consts[OB_O + tid] = ldw(ob, tid, isbf);
  if (tid == 0) {
    float a[12]; float m = -1e30f;
    for (int p = 0; p < 12; ++p) { a[p] = ldw(att, p, isbf); m = fmaxf(m, a[p]); }
    float ssum = 0.f;
    for (int p = 0; p < 12; ++p) { a[p] = __expf(a[p] - m); ssum += a[p]; }
    for (int p = 0; p < 12; ++p) consts[PR_O + p] = a[p] / ssum;
  }
}

// 2) single-pass adjacency build: one packed 64-bit atomic per edge gives BOTH the
//    slot index (count, hi32) and the weighted-degree accumulation (fixed point, lo32).
__global__ void k_append(const void* __restrict__ ei, const void* __restrict__ ea,
                         const int* __restrict__ flags,
                         unsigned long long* __restrict__ degcnt,
                         unsigned int* __restrict__ slab,
                         int* __restrict__ ovf_cnt, int* __restrict__ ovf_dst,
                         unsigned int* __restrict__ ovf_pack) {
  int isbf = flags[0], is64 = flags[1];
  int e = blockIdx.x * blockDim.x + threadIdx.x;
  if (e >= EE) return;
  int r, c;
  if (is64) {
    r = (int)((const unsigned int*)ei)[2 * e];
    c = (int)((const unsigned int*)ei)[2 * (EE + e)];
  } else {
    r = ((const int*)ei)[e];
    c = ((const int*)ei)[EE + e];
  }
  unsigned short wb;
  float w;
  if (isbf) { wb = ((const unsigned short*)ea)[e]; w = b2f(wb); }
  else      { w = ((const float*)ea)[e]; wb = f2b(w); }
  unsigned long long pk = (1ull << 32) |
      (unsigned long long)(unsigned int)__float2int_rn(w * 1048576.0f);
  unsigned long long old = atomicAdd(&degcnt[c], pk);
  int pos = (int)(old >> 32);
  unsigned int packed = ((unsigned int)wb << 16) | (unsigned int)r;
  if (pos < CAP) {
    slab[c * CAP + pos] = packed;
  } else {
    int oi = atomicAdd(ovf_cnt, 1);
    if (oi < OVCAP) { ovf_dst[oi] = c; ovf_pack[oi] = packed; }
  }
}

// 3) fused per-node pipeline, NPB nodes per block, 192 threads.
//    mega-stages all NPB nodes' edges once, then per-node gather->gates->out.
//    x layout [b][n][f][p]: per-node payload = 4 segments of 96 elems, stride NN*96.
__global__ void __launch_bounds__(192) k_node(
    const void* __restrict__ x,
    const unsigned long long* __restrict__ degcnt,
    const unsigned int* __restrict__ slab,
    const int* __restrict__ ovf_cnt, const int* __restrict__ ovf_dst,
    const unsigned int* __restrict__ ovf_pack,
    const float* __restrict__ consts, const int* __restrict__ flags,
    void* __restrict__ out) {
  __shared__ __align__(16) float sc[792];        // OW(768) OB(12) PR(12)
  __shared__ __align__(16) float pacc[4 * 384];
  __shared__ __align__(16) float acc[384];       // [b][p][f]
  __shared__ __align__(16) float hpart[768];     // [g3][b][k]
  __shared__ __align__(16) float hfin[256];      // [b][k]
  __shared__ int   sedge[NPB * LCAP];            // src*96 (elem offset)
  __shared__ float vedge[NPB * LCAP];            // w * dinv[src]
  __shared__ int   scnt[NPB];
  __shared__ float sdn[NPB];

  const int tid = threadIdx.x;
  const int isbf = flags[0];
  const int n0 = blockIdx.x * NPB;

  for (int i = tid; i < 792; i += 192) sc[i] = consts[OW_O + i];

  const int g  = tid / 48;      // edge subgroup 0..3
  const int c  = tid % 48;      // payload chunk: flat elems 8c..8c+7 of [b][f][p]
  const int k  = tid & 63;      // gate lane (hidden dim)
  const int g3 = tid >> 6;      // gate p-group 0..2
  const int bc = c / 12;
  const int oc = 8 * (c % 12);
  const long xoff = (long)bc * (NN * 96) + oc;   // + s*96 -> elem index in x[b][s][f][p]

  float wz[8], wh[8];
#pragma unroll
  for (int f = 0; f < 8; ++f) {
    wz[f] = consts[WZ_O + f * 64 + k];
    wh[f] = consts[WH_O + f * 64 + k];
  }
  const float bz = consts[BZ_O + k], bh = consts[BH_O + k];

  if (tid < NPB) {
    unsigned long long dc = degcnt[n0 + tid];
    int cnt = (int)(dc >> 32);
    scnt[tid] = cnt < CAP ? cnt : CAP;
    sdn[tid] = rsqrtf(degf(dc) + 1.0f);
  }
  __syncthreads();

  // mega-stage all NPB nodes' edges (reads degcnt directly to avoid scnt race)
  for (int i = tid; i < NPB * CAP; i += 192) {
    int ni = i >> 6, slot = i & (CAP - 1);
    int cnt = (int)(degcnt[n0 + ni] >> 32);
    if (cnt > CAP) cnt = CAP;
    if (slot < cnt) {
      unsigned int pk = slab[(n0 + ni) * CAP + slot];
      int s = (int)(pk & 0xffffu);
      float w = b2f((unsigned short)(pk >> 16));
      sedge[ni * LCAP + slot] = s * 96;
      vedge[ni * LCAP + slot] = w * rsqrtf(degf(degcnt[s]) + 1.0f);
    }
  }
  {
    int ov = ovf_cnt[0];                 // expected 0
    if (ov > 0) {
      if (ov > OVCAP) ov = OVCAP;
      for (int i = tid; i < ov; i += 192) {
        unsigned int dd = (unsigned int)(ovf_dst[i] - n0);
        if (dd < NPB) {
          int idx = atomicAdd(&scnt[dd], 1);
          if (idx < LCAP) {
            unsigned int pk = ovf_pack[i];
            int s = (int)(pk & 0xffffu);
            float w = b2f((unsigned short)(pk >> 16));
            sedge[dd * LCAP + idx] = s * 96;
            vedge[dd * LCAP + idx] = w * rsqrtf(degf(degcnt[s]) + 1.0f);
          }
        }
      }
    }
  }
  __syncthreads();

  for (int ni = 0; ni < NPB; ++ni) {
    const int n = n0 + ni;
    int m = scnt[ni]; if (m > LCAP) m = LCAP;
    const float dn = sdn[ni];
    float a[8];
#pragma unroll
    for (int t = 0; t < 8; ++t) a[t] = 0.f;

    if (isbf) {
      const unsigned short* xb = (const unsigned short*)x;
      for (int j = g; j < m; j += 4) {
        int soff = sedge[ni * LCAP + j];
        float v = vedge[ni * LCAP + j];
        uint4 u = *(const uint4*)(xb + xoff + soff);
        float x0, x1;
        upk(u.x, x0, x1); a[0] += v * x0; a[1] += v * x1;
        upk(u.y, x0, x1); a[2] += v * x0; a[3] += v * x1;
        upk(u.z, x0, x1); a[4] += v * x0; a[5] += v * x1;
        upk(u.w, x0, x1); a[6] += v * x0; a[7] += v * x1;
      }
      if (g == 0) {      // self loop (w=1): outer dn -> dn^2 * x[n]
        uint4 u = *(const uint4*)(xb + xoff + (long)n * 96);
        float x0, x1;
        upk(u.x, x0, x1); a[0] += dn * x0; a[1] += dn * x1;
        upk(u.y, x0, x1); a[2] += dn * x0; a[3] += dn * x1;
        upk(u.z, x0, x1); a[4] += dn * x0; a[5] += dn * x1;
        upk(u.w, x0, x1); a[6] += dn * x0; a[7] += dn * x1;
      }
    } else {
      const float* xf = (const float*)x;
      for (int j = g; j < m; j += 4) {
        int soff = sedge[ni * LCAP + j];
        float v = vedge[ni * LCAP + j];
        const float4* px = (const float4*)(xf + xoff + soff);
        float4 u0 = px[0], u1 = px[1];
        a[0] += v * u0.x; a[1] += v * u0.y; a[2] += v * u0.z; a[3] += v * u0.w;
        a[4] += v * u1.x; a[5] += v * u1.y; a[6] += v * u1.z; a[7] += v * u1.w;
      }
      if (g == 0) {
        const float4* px = (const float4*)(xf + xoff + (long)n * 96);
        float4 u0 = px[0], u1 = px[1];
        a[0] += dn * u0.x; a[1] += dn * u0.y; a[2] += dn * u0.z; a[3] += dn * u0.w;
        a[4] += dn * u1.x; a[5] += dn * u1.y; a[6] += dn * u1.z; a[7] += dn * u1.w;
      }
    }
    {
      float4* pg = (float4*)&pacc[g * 384 + 8 * c];
      pg[0] = make_float4(a[0], a[1], a[2], a[3]);
      pg[1] = make_float4(a[4], a[5], a[6], a[7]);
    }
    __syncthreads();
    // combine 4 partials + scale by dn; transpose [b][f][p] -> [b][p][f]
    for (int i = tid; i < 384; i += 192) {
      int b = i / 96, r = i % 96, p = r >> 3, f = r & 7;
      int src = b * 96 + f * 12 + p;
      acc[i] = dn * (pacc[src] + pacc[384 + src] + pacc[768 + src] + pacc[1152 + src]);
    }
    __syncthreads();

    // gates: g3 handles p in {g3, g3+3, g3+6, g3+9}; k = hidden index
    float hb0 = 0.f, hb1 = 0.f, hb2 = 0.f, hb3 = 0.f;
#pragma unroll
    for (int pi = 0; pi < 4; ++pi) {
      int p = g3 + 3 * pi;
      float pr = sc[780 + p];
#pragma unroll
      for (int b = 0; b < 4; ++b) {
        const float4* A = (const float4*)&acc[b * 96 + p * 8];
        float4 A0 = A[0], A1 = A[1];
        float za = bz + A0.x * wz[0] + A0.y * wz[1] + A0.z * wz[2] + A0.w * wz[3]
                      + A1.x * wz[4] + A1.y * wz[5] + A1.z * wz[6] + A1.w * wz[7];
        float ta = bh + A0.x * wh[0] + A0.y * wh[1] + A0.z * wh[2] + A0.w * wh[3]
                      + A1.x * wh[4] + A1.y * wh[5] + A1.z * wh[6] + A1.w * wh[7];
        // (1 - sigmoid(za)) * tanh(ta) = (eh-1) / ((1+ea)(1+eh)), ea=e^za, eh=e^{2ta}
        float ea = __expf(za);
        float eh = __expf(2.0f * fminf(ta, 40.0f));
        float cc = pr * (eh - 1.0f) * __builtin_amdgcn_rcpf((1.0f + ea) * (1.0f + eh));
        if (b == 0) hb0 += cc; else if (b == 1) hb1 += cc;
        else if (b == 2) hb2 += cc; else hb3 += cc;
      }
    }
    hpart[g3 * 256 +   0 + k] = hb0;
    hpart[g3 * 256 +  64 + k] = hb1;
    hpart[g3 * 256 + 128 + k] = hb2;
    hpart[g3 * 256 + 192 + k] = hb3;
    __syncthreads();
    for (int i = tid; i < 256; i += 192)
      hfin[i] = fmaxf(hpart[i] + hpart[256 + i] + hpart[512 + i], 0.f);
    __syncthreads();

    if (tid < 48) {
      int b = tid / 12, p = tid % 12;
      float o = sc[768 + p];
#pragma unroll 8
      for (int k2 = 0; k2 < 64; ++k2) o += hfin[b * 64 + k2] * sc[k2 * 12 + p];
      int oi = (b * NN + n) * 12 + p;
      if (isbf) ((unsigned short*)out)[oi] = f2b(o);
      else      ((float*)out)[oi] = o;
    }
  }
}

extern "C" void kernel_launch(void* const* d_in, const int* in_sizes, int n_in,
                              void* d_out, int out_size, void* d_ws, size_t ws_size,
                              hipStream_t stream) {
  const void* x   = d_in[0];
  const void* ei  = d_in[1];
  const void* ea  = d_in[2];
  const void* czw = d_in[3];
  const void* czb = d_in[4];
  // d_in[5], d_in[6]: conv_r_* — dead (H0 = 0)
  const void* chw = d_in[7];
  const void* chb = d_in[8];
  const void* lzw = d_in[9];
  const void* lzb = d_in[10];
  // d_in[11], d_in[12]: lin_r_* — dead
  const void* lhw = d_in[13];
  const void* lhb = d_in[14];
  const void* att = d_in[15];
  const void* ow  = d_in[16];
  const void* ob  = d_in[17];

  // workspace ~5.4 MB
  char* ws = (char*)d_ws;
  int*   flags   = (int*)  (ws + 0);
  float* consts  = (float*)(ws + 256);          // 1944 f32 -> ends 8032
  unsigned long long* degcnt = (unsigned long long*)(ws + 8192);   // 160000 -> 168192
  int*   ovf_cnt = (int*)  (ws + 168192);
  int*   ovf_dst = (int*)  (ws + 168448);       // 32768 -> 201216
  unsigned int* ovf_pack = (unsigned int*)(ws + 201216);  // 32768 -> 233984
  unsigned int* slab     = (unsigned int*)(ws + 240000);  // 5,120,000 -> 5,360,000

  k_init<<<dim3(79), dim3(256), 0, stream>>>((const unsigned int*)ei,
                                             (const unsigned int*)ea, flags, degcnt,
                                             ovf_cnt, consts, czw, czb, chw, chb,
                                             lzw, lzb, lhw, lhb, att, ow, ob);
  k_append<<<dim3(1250), dim3(256), 0, stream>>>(ei, ea, flags, degcnt, slab,
                                                 ovf_cnt, ovf_dst, ovf_pack);
  k_node<<<dim3(NN / NPB), dim3(192), 0, stream>>>(x, degcnt, slab, ovf_cnt, ovf_dst,
                                                   ovf_pack, consts, flags, d_out);
}